// Round 2
// baseline (393.238 us; speedup 1.0000x reference)
//
#include <hip/hip_runtime.h>

// Depthwise 7x7 cross-correlation, same padding.
// x: [8,256,64,64] fp32; tmpl: [8,8,256,7,7] fp32; out: [8,8,256,64,64] fp32.
//
// One block per (b,c) plane. Plane staged once into zero-padded LDS
// (70 x 72, left pad 4 => 16B-aligned rows). Each WAVE owns one template
// per pass (t is wave-uniform via readfirstlane => taps scalarize into
// SGPRs, keeping VGPR pressure ~60). Each lane computes a 4-col x 8-row
// strip with a sliding row window: every input row is read once
// (3 x ds_read_b128) and feeds up to 7 live float4 accumulators.

#define NT 8
#define BS 8
#define NC 256
#define HW 64
#define PLANE (HW * HW)
#define LROWS 70
#define LSTR  72

__global__ __launch_bounds__(256) void dwxcorr_kernel(
    const float* __restrict__ x,
    const float* __restrict__ tm,
    float* __restrict__ out)
{
    __shared__ __align__(16) float xpl[LROWS * LSTR];   // 20160 B

    const int bc  = blockIdx.x;       // b*256 + c
    const int tid = threadIdx.x;

    // ---- zero padded plane, then stage interior (coalesced float4) ----
    for (int i = tid; i < LROWS * LSTR; i += 256) xpl[i] = 0.0f;
    __syncthreads();
    const float* xp = x + (size_t)bc * PLANE;
    for (int i = tid; i < PLANE / 4; i += 256) {
        float4 v = ((const float4*)xp)[i];
        int row = i >> 4;              // 16 float4 per 64-wide row
        int c4  = (i & 15) << 2;
        *(float4*)&xpl[(row + 3) * LSTR + 4 + c4] = v;
    }
    __syncthreads();

    const int lane  = tid & 63;
    const int wv    = __builtin_amdgcn_readfirstlane(tid >> 6); // 0..3, uniform
    const int tx    = lane & 15;                 // col tile: cols 4*tx..+3
    const int sy    = lane >> 4;                 // 0..3
    const int strip = ((wv & 1) << 2) + sy;      // 0..7 -> rows 8*strip..+7
    const int row0  = strip << 3;
    const int col0  = tx << 2;

    #pragma unroll 1
    for (int p = 0; p < 4; ++p) {
        const int t = (p << 1) + (wv >> 1);      // wave-uniform template id

        // taps: wave-uniform address -> s_load into SGPRs
        const float* wp = tm + ((size_t)t * (BS * NC) + bc) * 49;
        float w[49];
        #pragma unroll
        for (int k = 0; k < 49; ++k) w[k] = wp[k];

        float4 acc[7];
        #pragma unroll
        for (int k = 0; k < 7; ++k) acc[k] = make_float4(0.f, 0.f, 0.f, 0.f);

        float* op = out + ((size_t)t * (BS * NC) + bc) * PLANE + row0 * HW + col0;

        // slide over input rows: LDS rows row0..row0+13
        #pragma unroll
        for (int ir = 0; ir < 14; ++ir) {
            const float* rowp = &xpl[(row0 + ir) * LSTR + col0];
            float4 a = *(const float4*)(rowp);
            float4 b = *(const float4*)(rowp + 4);
            float4 c = *(const float4*)(rowp + 8);
            const float xw[12] = {a.x, a.y, a.z, a.w,
                                  b.x, b.y, b.z, b.w,
                                  c.x, c.y, c.z, c.w};

            #pragma unroll
            for (int ky = 0; ky < 7; ++ky) {
                const int r = ir - ky;           // output row fed by this ky
                if (r >= 0 && r < 8) {
                    const int sl = r % 7;        // constant after unroll
                    #pragma unroll
                    for (int kx = 0; kx < 7; ++kx) {
                        const float tv = w[ky * 7 + kx];
                        acc[sl].x = fmaf(xw[kx + 1], tv, acc[sl].x);
                        acc[sl].y = fmaf(xw[kx + 2], tv, acc[sl].y);
                        acc[sl].z = fmaf(xw[kx + 3], tv, acc[sl].z);
                        acc[sl].w = fmaf(xw[kx + 4], tv, acc[sl].w);
                    }
                }
            }

            // retire completed output row r = ir-6, free its slot
            if (ir >= 6) {
                const int r  = ir - 6;
                const int sl = r % 7;
                *(float4*)(op + r * HW) = acc[sl];
                acc[sl] = make_float4(0.f, 0.f, 0.f, 0.f);
            }
        }
    }
}

extern "C" void kernel_launch(void* const* d_in, const int* in_sizes, int n_in,
                              void* d_out, int out_size, void* d_ws, size_t ws_size,
                              hipStream_t stream) {
    const float* x  = (const float*)d_in[0];
    const float* tm = (const float*)d_in[1];
    float* out = (float*)d_out;
    dwxcorr_kernel<<<BS * NC, 256, 0, stream>>>(x, tm, out);
}